// Round 1
// baseline (1255.774 us; speedup 1.0000x reference)
//
#include <hip/hip_runtime.h>
#include <hip/hip_bf16.h>

#define N_NODES  60000
#define N_EDGES  240000
#define N_REL    4
#define N_GRAPHS 128
#define D_IN     768
#define D_H      256
#define N_LAYERS 6
#define M_PAD    60032            // 469 * 128
#define N_TOT    1280             // L0: 256 root + 4*256 msg
#define BM_L     64               // fused layer: dst rows per block
#define LDM      264              // mean tile row stride (256 + 8 shorts = +16B pad)

static inline int cdiv(int a, int b) { return (a + b - 1) / b; }

typedef __attribute__((ext_vector_type(8))) short short8;
typedef __attribute__((ext_vector_type(4))) float f32x4;

__device__ __forceinline__ float bf2f(unsigned short u) {
    union { unsigned int i; float f; } c; c.i = ((unsigned int)u) << 16; return c.f;
}
__device__ __forceinline__ float bflo(unsigned int u) {
    union { unsigned int i; float f; } c; c.i = u << 16; return c.f;
}
__device__ __forceinline__ float bfhi(unsigned int u) {
    union { unsigned int i; float f; } c; c.i = u & 0xffff0000u; return c.f;
}
__device__ __forceinline__ unsigned short f2bf(float f) {
    union { float f; unsigned int i; } c; c.f = f;
    unsigned int i = c.i;
    unsigned int r = (i + 0x7FFFu + ((i >> 16) & 1u)) >> 16;   // RNE
    return (unsigned short)r;
}

__device__ __forceinline__ void gload16(const void* g, void* l) {
    __builtin_amdgcn_global_load_lds((const __attribute__((address_space(1))) void*)g,
                                     (__attribute__((address_space(3))) void*)l, 16, 0, 0);
}

// ---------------------------------------------------------------------------
// Layer-0 GEMM (transform-first): A[M_PAD,768] bf16 @ Wt0[1280,768]^T.
// Double-buffered LDS (stage t+1 while computing t -> vmcnt drain overlaps MFMA).
// XCD-chunked remap: each XCD gets a contiguous band of row-blocks, sweeping
// the 5 col-blocks of a row consecutively -> A row-panel stays in that XCD's L2.
// grid = 8 * 295 (15 tail blocks idle).
// ---------------------------------------------------------------------------
__global__ __launch_bounds__(512) void gemm_l0(
    const unsigned short* __restrict__ A,
    const unsigned short* __restrict__ Bt,
    const float* __restrict__ bias,
    unsigned short* __restrict__ out_root,
    unsigned short* __restrict__ out_msg,
    int K)
{
    __shared__ __align__(16) unsigned short S[2][(128 + 256) * 32];   // 2 x 24576 B

    // --- XCD-chunked tile remap (8 XCDs; xcd<5 -> 59 row-blocks, else 58) ---
    const int bid  = blockIdx.x;
    const int xcd  = bid & 7;
    const int j    = bid >> 3;                       // 0..294
    const int nrow = (xcd < 5) ? 59 : 58;
    const int rbase = (xcd < 5) ? xcd * 59 : 295 + (xcd - 5) * 58;
    const int rr = j / 5, cc = j % 5;
    if (rr >= nrow) return;
    const int bm = (rbase + rr) * 128;
    const int bn = cc * 256;

    const int tid  = threadIdx.x;
    const int wave = tid >> 6, lane = tid & 63;
    const int wm = (wave & 1) * 64, wn = (wave >> 1) * 64;

    const int lr = lane >> 2;
    const int kg = ((lane & 3) ^ ((lr ^ (lr >> 2)) & 3)) * 8;   // swizzled k-chunk
    const unsigned short* gsrc[3];
    int ldoff[3];
    #pragma unroll
    for (int t = 0; t < 3; ++t) {
        int g = wave * 3 + t;
        if (g < 8) {
            gsrc[t] = A + (size_t)(bm + g * 16 + lr) * K + kg;
            ldoff[t] = g * 512;                       // As region: shorts 0..4095
        } else {
            gsrc[t] = Bt + (size_t)(bn + (g - 8) * 16 + lr) * K + kg;
            ldoff[t] = 4096 + (g - 8) * 512;          // Bs region: shorts 4096..12287
        }
    }

    f32x4 acc[4][4] = {};
    const int fr = lane & 15;
    const int qsw = (((lane >> 4) ^ fr ^ (fr >> 2)) & 3) * 8;

    const int nstep = K >> 5;                         // 24
    gload16(gsrc[0], S[0] + ldoff[0]);
    gload16(gsrc[1], S[0] + ldoff[1]);
    gload16(gsrc[2], S[0] + ldoff[2]);
    __syncthreads();                                  // slice 0 staged

    #pragma unroll 1
    for (int t = 0; t < nstep; ++t) {
        if (t + 1 < nstep) {                          // stage ahead into alt buffer
            unsigned short* nb = S[(t + 1) & 1];
            gload16(gsrc[0] + (t + 1) * 32, nb + ldoff[0]);
            gload16(gsrc[1] + (t + 1) * 32, nb + ldoff[1]);
            gload16(gsrc[2] + (t + 1) * 32, nb + ldoff[2]);
        }
        const unsigned short* cur = S[t & 1];
        short8 a[4], b[4];
        #pragma unroll
        for (int q = 0; q < 4; ++q) {
            a[q] = *(const short8*)&cur[(wm + q * 16 + fr) * 32 + qsw];
            b[q] = *(const short8*)&cur[4096 + (wn + q * 16 + fr) * 32 + qsw];
        }
        #pragma unroll
        for (int mt = 0; mt < 4; ++mt)
            #pragma unroll
            for (int nt = 0; nt < 4; ++nt)
                acc[mt][nt] = __builtin_amdgcn_mfma_f32_16x16x32_bf16(
                    a[mt], b[nt], acc[mt][nt], 0, 0, 0);
        __syncthreads();   // drains vmcnt(0): stage(t+1) done; reads of S[(t+1)&1] done
    }

    const bool is_root = (bn == 0);   // block-uniform
    #pragma unroll
    for (int mt = 0; mt < 4; ++mt) {
        #pragma unroll
        for (int nt = 0; nt < 4; ++nt) {
            int col = bn + wn + nt * 16 + fr;
            float bv = bias[col];
            #pragma unroll
            for (int r = 0; r < 4; ++r) {
                int row = bm + wm + mt * 16 + ((lane >> 4) << 2) + r;
                float v = acc[mt][nt][r] + bv;
                if (is_root) out_root[(size_t)row * 256 + col] = f2bf(v);
                else         out_msg[(size_t)row * 1024 + (col - 256)] = f2bf(v);
            }
        }
    }
}

// ---------------------------------------------------------------------------
// Fused RGCN mid-layer, v2:
//  - cooperative gather: half-wave (32 lanes) per node, uint4/lane -> one
//    contiguous 512 B h-row per edge, edge-loop bounds uniform per half-wave
//    (kills the 64-lane max-degree divergence and the 64-line scatter).
//  - double-buffered Bs with stage-ahead: W slice idx+1 issued before the
//    MFMAs of slice idx; the __syncthreads vmcnt(0) drain overlaps compute.
//  Barriers/block: 90 -> 44.  LDS 66.5 KB -> 2 blocks/CU.
// ---------------------------------------------------------------------------
__global__ __launch_bounds__(512) void rgcn_layer(
    const unsigned short* __restrict__ h,     // [M_PAD, 256]
    const unsigned short* __restrict__ Wl,    // [256 out][1280 k]
    const float* __restrict__ bias,           // [256]
    const int* __restrict__ rp4,              // [4*N_NODES + 1]
    const int* __restrict__ e_srcs,           // [E] srcs sorted by (dst, rel)
    const float* __restrict__ inv4,           // [N_NODES*4]
    unsigned short* __restrict__ h_out)       // [M_PAD, 256]
{
    __shared__ __align__(16) unsigned short mt[BM_L * LDM];   // 33792 B mean/self tile
    __shared__ __align__(16) unsigned short Bsd[2][256 * 32]; // 2 x 16384 B weight tiles

    const int tid  = threadIdx.x;
    const int wave = tid >> 6, lane = tid & 63;
    const int bm = blockIdx.x * BM_L;

    // B staging: wave stages rows g0*16.. , swizzled 8-short chunks
    const int lr = lane >> 2;
    const int kg = ((lane & 3) ^ ((lr ^ (lr >> 2)) & 3)) * 8;
    const int g0 = wave * 2;
    const unsigned short* wsrc0 = Wl + (size_t)(g0 * 16 + lr) * N_TOT + kg;
    const unsigned short* wsrc1 = Wl + (size_t)((g0 + 1) * 16 + lr) * N_TOT + kg;

    // MFMA mapping
    const int fr  = lane & 15;
    const int q8  = (lane >> 4) * 8;
    const int qsw = (((lane >> 4) ^ fr ^ (fr >> 2)) & 3) * 8;
    const int wcol = wave * 32;

    // gather mapping: half-wave owns a node, lane covers bf16 cols l32*8..+7
    const int half = lane >> 5;
    const int l32  = lane & 31;

    f32x4 acc[4][2] = {};

    // ---- stage k-slice 0 (relation 0, kk 0) ----
    gload16(wsrc0, Bsd[0] + g0 * 512);
    gload16(wsrc1, Bsd[0] + (g0 + 1) * 512);

    // ---- gather phase p (p<4: mean over relation-p edges; p==4: self row) ----
    auto gather_phase = [&](int p) {
        #pragma unroll 1
        for (int i = 0; i < 4; ++i) {
            int row  = wave * 8 + 2 * i + half;      // local row 0..63
            int node = bm + row;
            float4 s0 = make_float4(0.f, 0.f, 0.f, 0.f);
            float4 s1 = make_float4(0.f, 0.f, 0.f, 0.f);
            if (node < N_NODES) {
                if (p == 4) {
                    uint4 q = *(const uint4*)&h[(size_t)node * 256 + l32 * 8];
                    s0.x = bflo(q.x); s0.y = bfhi(q.x); s0.z = bflo(q.y); s0.w = bfhi(q.y);
                    s1.x = bflo(q.z); s1.y = bfhi(q.z); s1.z = bflo(q.w); s1.w = bfhi(q.w);
                } else {
                    int lo = rp4[node * 4 + p], hi = rp4[node * 4 + p + 1];
                    for (int e = lo; e < hi; ++e) {
                        int s = e_srcs[e];
                        uint4 q = *(const uint4*)&h[(size_t)s * 256 + l32 * 8];
                        s0.x += bflo(q.x); s0.y += bfhi(q.x);
                        s0.z += bflo(q.y); s0.w += bfhi(q.y);
                        s1.x += bflo(q.z); s1.y += bfhi(q.z);
                        s1.z += bflo(q.w); s1.w += bfhi(q.w);
                    }
                    float sc = inv4[node * 4 + p];
                    s0.x *= sc; s0.y *= sc; s0.z *= sc; s0.w *= sc;
                    s1.x *= sc; s1.y *= sc; s1.z *= sc; s1.w *= sc;
                }
            }
            ushort4 o0, o1;
            o0.x = f2bf(s0.x); o0.y = f2bf(s0.y); o0.z = f2bf(s0.z); o0.w = f2bf(s0.w);
            o1.x = f2bf(s1.x); o1.y = f2bf(s1.y); o1.z = f2bf(s1.z); o1.w = f2bf(s1.w);
            unsigned short* d = &mt[row * LDM + l32 * 8];
            *(ushort4*)d       = o0;
            *(ushort4*)(d + 4) = o1;
        }
    };

    gather_phase(0);
    __syncthreads();       // mt(phase 0) visible; slice 0 staged (vmcnt drained)

    #pragma unroll 1
    for (int r = 0; r < 5; ++r) {
        #pragma unroll 1
        for (int kk = 0; kk < 8; ++kk) {
            const int idx = r * 8 + kk;               // global k-slice 0..39
            if (idx < 39) {                           // stage ahead into alt buffer
                unsigned short* nb = Bsd[(idx + 1) & 1];
                gload16(wsrc0 + (idx + 1) * 32, nb + g0 * 512);
                gload16(wsrc1 + (idx + 1) * 32, nb + (g0 + 1) * 512);
            }
            const unsigned short* cb = Bsd[idx & 1];
            short8 a[4], b[2];
            #pragma unroll
            for (int i = 0; i < 4; ++i)
                a[i] = *(const short8*)&mt[(i * 16 + fr) * LDM + kk * 32 + q8];
            #pragma unroll
            for (int nt = 0; nt < 2; ++nt)
                b[nt] = *(const short8*)&cb[(wcol + nt * 16 + fr) * 32 + qsw];
            #pragma unroll
            for (int i = 0; i < 4; ++i)
                #pragma unroll
                for (int nt = 0; nt < 2; ++nt)
                    acc[i][nt] = __builtin_amdgcn_mfma_f32_16x16x32_bf16(
                        a[i], b[nt], acc[i][nt], 0, 0, 0);
            __syncthreads();  // drains vmcnt(0): stage(idx+1) done; Bsd reads done
        }
        if (r < 4) {
            gather_phase(r + 1);   // mt rewrite safe: a-reads drained at last barrier
            __syncthreads();       // mt(phase r+1) visible to all waves
        }
    }

    // ---- epilogue: +bias, ReLU, bf16 ----
    #pragma unroll
    for (int i = 0; i < 4; ++i) {
        #pragma unroll
        for (int nt = 0; nt < 2; ++nt) {
            int col = wcol + nt * 16 + fr;
            float bv = bias[col];
            #pragma unroll
            for (int rg = 0; rg < 4; ++rg) {
                int row = bm + i * 16 + ((lane >> 4) << 2) + rg;
                float v = fmaxf(acc[i][nt][rg] + bv, 0.f);
                h_out[(size_t)row * 256 + col] = f2bf(v);
            }
        }
    }
}

// ---------------------------------------------------------------------------
// Prep kernels
// ---------------------------------------------------------------------------
__global__ void convert_x(const float* __restrict__ x, unsigned short* __restrict__ xb) {
    size_t i = ((size_t)blockIdx.x * 256 + threadIdx.x) * 4;
    if (i >= (size_t)M_PAD * D_IN) return;
    ushort4 o;
    if (i < (size_t)N_NODES * D_IN) {
        float4 v = *(const float4*)&x[i];
        o.x = f2bf(v.x); o.y = f2bf(v.y); o.z = f2bf(v.z); o.w = f2bf(v.w);
    } else {
        o.x = o.y = o.z = o.w = 0;
    }
    *(ushort4*)&xb[i] = o;
}

__global__ void pack_w0(const float* __restrict__ root0, const float* __restrict__ w0,
                        unsigned short* __restrict__ Wt0) {
    int idx = blockIdx.x * 256 + threadIdx.x;            // Wt0[n][k], [1280 x 768]
    if (idx >= N_TOT * D_IN) return;
    int k = idx % D_IN, n = idx / D_IN;
    float v = (n < 256) ? root0[k * 256 + n]
                        : w0[(((n >> 8) - 1) * D_IN + k) * 256 + (n & 255)];
    Wt0[idx] = f2bf(v);
}

// WtR[l][n][k]: k<1024 -> w_rest[l][k>>8][k&255][n]; k>=1024 -> root_rest[l][k-1024][n]
__global__ void pack_wr(const float* __restrict__ root_rest, const float* __restrict__ w_rest,
                        unsigned short* __restrict__ WtR) {
    int idx = blockIdx.x * 256 + threadIdx.x;
    if (idx >= 5 * 256 * N_TOT) return;
    int k = idx % N_TOT; int t = idx / N_TOT; int n = t & 255; int l = t >> 8;
    float v = (k < 1024)
        ? w_rest[(((l * 4 + (k >> 8)) * 256) + (k & 255)) * 256 + n]
        : root_rest[(l * 256 + (k - 1024)) * 256 + n];
    WtR[idx] = f2bf(v);
}

__global__ void build_bias(const float* __restrict__ b0, float* __restrict__ eb) {
    int i = blockIdx.x * 256 + threadIdx.x;
    if (i < N_TOT) eb[i] = (i < 256) ? b0[i] : 0.f;
}

// ---------------------------------------------------------------------------
// (dst, rel)-sorted CSR over 4*N segments
// ---------------------------------------------------------------------------
__global__ void deg4_count(const int* __restrict__ dst, const int* __restrict__ rel,
                           int* __restrict__ deg4, int E) {
    int e = blockIdx.x * 256 + threadIdx.x;
    if (e < E) atomicAdd(&deg4[dst[e] * 4 + rel[e]], 1);
}

__global__ void invert4(const int* __restrict__ deg4, float* __restrict__ inv4, int n) {
    int i = blockIdx.x * 256 + threadIdx.x;
    if (i < n) inv4[i] = 1.0f / (float)max(deg4[i], 1);
}

__global__ __launch_bounds__(256) void block_sum(const int* __restrict__ deg,
                                                 int* __restrict__ bsum, int n) {
    __shared__ int s[256];
    int i = blockIdx.x * 256 + threadIdx.x;
    s[threadIdx.x] = (i < n) ? deg[i] : 0;
    __syncthreads();
    for (int o = 128; o > 0; o >>= 1) {
        if (threadIdx.x < o) s[threadIdx.x] += s[threadIdx.x + o];
        __syncthreads();
    }
    if (threadIdx.x == 0) bsum[blockIdx.x] = s[0];
}

__global__ __launch_bounds__(1024) void scan_bsum(const int* __restrict__ bsum,
                                                  int* __restrict__ boff, int nb) {
    __shared__ int s[1024];
    int t = threadIdx.x;
    int v0 = (t < nb) ? bsum[t] : 0;
    s[t] = v0;
    __syncthreads();
    for (int o = 1; o < 1024; o <<= 1) {
        int v = (t >= o) ? s[t - o] : 0;
        __syncthreads();
        s[t] += v;
        __syncthreads();
    }
    if (t < nb) boff[t] = s[t] - v0;   // exclusive
}

__global__ __launch_bounds__(256) void block_scan_write(
    const int* __restrict__ deg, const int* __restrict__ boff,
    int* __restrict__ row_ptr, int* __restrict__ cursor, int n, int total) {
    __shared__ int s[256];
    int t = threadIdx.x;
    int i = blockIdx.x * 256 + t;
    int v = (i < n) ? deg[i] : 0;
    s[t] = v;
    __syncthreads();
    for (int o = 1; o < 256; o <<= 1) {
        int u = (t >= o) ? s[t - o] : 0;
        __syncthreads();
        s[t] += u;
        __syncthreads();
    }
    int excl = s[t] - v + boff[blockIdx.x];
    if (i < n) { row_ptr[i] = excl; cursor[i] = excl; }
    if (blockIdx.x == 0 && t == 0) row_ptr[n] = total;
}

__global__ void place_edges4(const int* __restrict__ dst, const int* __restrict__ src,
                             const int* __restrict__ rel, int* __restrict__ cursor,
                             int* __restrict__ e_srcs, int E) {
    int e = blockIdx.x * 256 + threadIdx.x;
    if (e < E) {
        int p = atomicAdd(&cursor[dst[e] * 4 + rel[e]], 1);
        e_srcs[p] = src[e];
    }
}

// ---------------------------------------------------------------------------
// Layer-0 aggregate: h0 = relu(root[n] + sum_r inv_r * sum_e msg[src, r])
// ---------------------------------------------------------------------------
__global__ __launch_bounds__(256) void aggregate0(
    const unsigned short* __restrict__ rootb,   // [M_PAD,256]
    const unsigned short* __restrict__ msg,     // [M_PAD,1024]
    const int* __restrict__ rp4, const int* __restrict__ e_srcs,
    const float* __restrict__ inv4,
    unsigned short* __restrict__ h_out)         // [M_PAD,256]
{
    int node = blockIdx.x * 4 + (threadIdx.x >> 6);
    if (node >= N_NODES) return;
    int lane = threadIdx.x & 63;
    float4 iv = *(const float4*)&inv4[(size_t)node * 4];

    ushort4 rt = *(const ushort4*)&rootb[(size_t)node * 256 + lane * 4];
    float4 acc = make_float4(bf2f(rt.x), bf2f(rt.y), bf2f(rt.z), bf2f(rt.w));

    #pragma unroll
    for (int r = 0; r < 4; ++r) {
        int lo = rp4[(size_t)node * 4 + r], hi = rp4[(size_t)node * 4 + r + 1];
        float f = (r == 0) ? iv.x : (r == 1) ? iv.y : (r == 2) ? iv.z : iv.w;
        float4 s4 = make_float4(0, 0, 0, 0);
        for (int e = lo; e < hi; ++e) {
            int s = e_srcs[e];
            ushort4 m = *(const ushort4*)&msg[(size_t)s * 1024 + (r << 8) + lane * 4];
            s4.x += bf2f(m.x); s4.y += bf2f(m.y);
            s4.z += bf2f(m.z); s4.w += bf2f(m.w);
        }
        acc.x += s4.x * f; acc.y += s4.y * f;
        acc.z += s4.z * f; acc.w += s4.w * f;
    }
    ushort4 o;
    o.x = f2bf(fmaxf(acc.x, 0.f));
    o.y = f2bf(fmaxf(acc.y, 0.f));
    o.z = f2bf(fmaxf(acc.z, 0.f));
    o.w = f2bf(fmaxf(acc.w, 0.f));
    *(ushort4*)&h_out[(size_t)node * 256 + lane * 4] = o;
}

// ---------------------------------------------------------------------------
// Pooling + MLP head
// ---------------------------------------------------------------------------
__global__ __launch_bounds__(256) void pool_kernel(
    const unsigned short* __restrict__ h, const int* __restrict__ batch,
    float* __restrict__ g_feat)
{
    int g = blockIdx.x;
    int t = threadIdx.x;
    __shared__ int s_lo, s_hi;
    if (t == 0) {
        int lo = 0, hi = N_NODES;
        while (lo < hi) { int m = (lo + hi) >> 1; if (batch[m] < g) lo = m + 1; else hi = m; }
        s_lo = lo;
        int lo2 = lo, hi2 = N_NODES;
        while (lo2 < hi2) { int m = (lo2 + hi2) >> 1; if (batch[m] < g + 1) lo2 = m + 1; else hi2 = m; }
        s_hi = lo2;
    }
    __syncthreads();
    int lo = s_lo, hi = s_hi;
    float sum = 0.f, mx = 0.f;   // post-ReLU
    for (int n = lo; n < hi; ++n) {
        float v = bf2f(h[(size_t)n * 256 + t]);
        sum += v;
        mx = fmaxf(mx, v);
    }
    float cnt = (float)(hi - lo);
    g_feat[g * 512 + t]       = sum / fmaxf(cnt, 1.0f);
    g_feat[g * 512 + 256 + t] = (cnt > 0.f) ? mx : 0.f;
}

__global__ __launch_bounds__(128) void mlp_head(
    const float* __restrict__ g_feat,
    const float* __restrict__ fc1_w, const float* __restrict__ fc1_b,
    const float* __restrict__ fc2_w, const float* __restrict__ fc2_b,
    float* __restrict__ out)
{
    __shared__ float gf[512];
    __shared__ float partial[2];
    int g = blockIdx.x, t = threadIdx.x;
    for (int i = t; i < 512; i += 128) gf[i] = g_feat[g * 512 + i];
    __syncthreads();
    float acc = fc1_b[t];
    for (int i = 0; i < 512; ++i) acc += gf[i] * fc1_w[i * 128 + t];
    float h1 = fmaxf(acc, 0.f);
    float v = h1 * fc2_w[t];
    #pragma unroll
    for (int off = 32; off > 0; off >>= 1) v += __shfl_down(v, off);
    if ((t & 63) == 0) partial[t >> 6] = v;
    __syncthreads();
    if (t == 0) {
        float s = partial[0] + partial[1] + fc2_b[0];
        out[g] = 1.0f / (1.0f + expf(-s));
    }
}

// ---------------------------------------------------------------------------
// Launch
// ---------------------------------------------------------------------------
extern "C" void kernel_launch(void* const* d_in, const int* in_sizes, int n_in,
                              void* d_out, int out_size, void* d_ws, size_t ws_size,
                              hipStream_t stream) {
    const float* x          = (const float*)d_in[0];
    const int*   edge_index = (const int*)d_in[1];
    const int*   edge_attr  = (const int*)d_in[2];
    const int*   batch      = (const int*)d_in[3];
    const float* w0         = (const float*)d_in[4];
    const float* root0      = (const float*)d_in[5];
    const float* b0         = (const float*)d_in[6];
    const float* w_rest     = (const float*)d_in[7];
    const float* root_rest  = (const float*)d_in[8];
    const float* b_rest     = (const float*)d_in[9];
    const float* fc1_w      = (const float*)d_in[10];
    const float* fc1_b      = (const float*)d_in[11];
    const float* fc2_w      = (const float*)d_in[12];
    const float* fc2_b      = (const float*)d_in[13];
    float* out = (float*)d_out;

    const int* e_src = edge_index;
    const int* e_dst = edge_index + N_EDGES;

    char* p = (char*)d_ws;
    auto alloc = [&](size_t bytes) { char* q = p; p += (bytes + 255) & ~(size_t)255; return q; };
    unsigned short* x_bf   = (unsigned short*)alloc((size_t)M_PAD * D_IN * 2);   // 92 MB
    unsigned short* msgbuf = (unsigned short*)alloc((size_t)M_PAD * 1024 * 2);   // 123 MB
    unsigned short* hA     = (unsigned short*)alloc((size_t)M_PAD * 256 * 2);    // 31 MB
    unsigned short* hB     = (unsigned short*)alloc((size_t)M_PAD * 256 * 2);    // 31 MB
    unsigned short* Wt0    = (unsigned short*)alloc((size_t)N_TOT * D_IN * 2);
    unsigned short* WtR    = (unsigned short*)alloc((size_t)5 * 256 * N_TOT * 2);
    float*          ebias  = (float*)alloc(N_TOT * 4);
    float*          inv4   = (float*)alloc((size_t)N_NODES * 4 * 4);
    float*          g_feat = (float*)alloc((size_t)N_GRAPHS * 512 * 4);
    int*            deg4   = (int*)alloc((size_t)N_NODES * 4 * 4);
    int*            rp4    = (int*)alloc(((size_t)N_NODES * 4 + 1) * 4);
    int*            cursor4= (int*)alloc((size_t)N_NODES * 4 * 4);
    int*            bsum   = (int*)alloc(1024 * 4);
    int*            boff   = (int*)alloc(1024 * 4);
    int*            e_srcs = (int*)alloc((size_t)N_EDGES * 4);

    const int n4 = N_NODES * 4;                 // 240000
    const int nscan4 = cdiv(n4, 256);           // 938

    // --- prep ---
    hipMemsetAsync(deg4, 0, (size_t)n4 * 4, stream);
    convert_x<<<cdiv(M_PAD * D_IN / 4, 256), 256, 0, stream>>>(x, x_bf);
    pack_w0<<<cdiv(N_TOT * D_IN, 256), 256, 0, stream>>>(root0, w0, Wt0);
    pack_wr<<<cdiv(5 * 256 * N_TOT, 256), 256, 0, stream>>>(root_rest, w_rest, WtR);
    build_bias<<<cdiv(N_TOT, 256), 256, 0, stream>>>(b0, ebias);
    deg4_count<<<cdiv(N_EDGES, 256), 256, 0, stream>>>(e_dst, edge_attr, deg4, N_EDGES);
    invert4<<<cdiv(n4, 256), 256, 0, stream>>>(deg4, inv4, n4);
    block_sum<<<nscan4, 256, 0, stream>>>(deg4, bsum, n4);
    scan_bsum<<<1, 1024, 0, stream>>>(bsum, boff, nscan4);
    block_scan_write<<<nscan4, 256, 0, stream>>>(deg4, boff, rp4, cursor4, n4, N_EDGES);
    place_edges4<<<cdiv(N_EDGES, 256), 256, 0, stream>>>(e_dst, e_src, edge_attr,
                                                         cursor4, e_srcs, N_EDGES);

    // --- layer 0: transform-first GEMM (XCD-chunked tiles, double-buffered) ---
    gemm_l0<<<8 * 295, 512, 0, stream>>>(x_bf, Wt0, ebias, hB, msgbuf, D_IN);
    aggregate0<<<cdiv(N_NODES, 4), 256, 0, stream>>>(hB, msgbuf, rp4, e_srcs, inv4, hA);

    // --- layers 1..5: fused gather+mean+GEMM ---
    unsigned short* cur = hA;
    unsigned short* nxt = hB;
    for (int L = 1; L < N_LAYERS; ++L) {
        rgcn_layer<<<M_PAD / BM_L, 512, 0, stream>>>(
            cur, WtR + (size_t)(L - 1) * 256 * N_TOT, b_rest + (size_t)(L - 1) * 256,
            rp4, e_srcs, inv4, nxt);
        unsigned short* t = cur; cur = nxt; nxt = t;
    }
    // final h in cur

    pool_kernel<<<N_GRAPHS, 256, 0, stream>>>(cur, batch, g_feat);
    mlp_head<<<N_GRAPHS, 128, 0, stream>>>(g_feat, fc1_w, fc1_b, fc2_w, fc2_b, out);
}

// Round 3
// 1160.296 us; speedup vs baseline: 1.0823x; 1.0823x over previous
//
#include <hip/hip_runtime.h>
#include <hip/hip_bf16.h>

#define N_NODES  60000
#define N_EDGES  240000
#define N_REL    4
#define N_GRAPHS 128
#define D_IN     768
#define D_H      256
#define N_LAYERS 6
#define M_PAD    60032            // 469 * 128
#define N_TOT    1280             // L0: 256 root + 4*256 msg; layers: 1024 agg + 256 self

static inline int cdiv(int a, int b) { return (a + b - 1) / b; }

typedef __attribute__((ext_vector_type(8))) short short8;
typedef __attribute__((ext_vector_type(4))) float f32x4;

__device__ __forceinline__ float bf2f(unsigned short u) {
    union { unsigned int i; float f; } c; c.i = ((unsigned int)u) << 16; return c.f;
}
__device__ __forceinline__ float bflo(unsigned int u) {
    union { unsigned int i; float f; } c; c.i = u << 16; return c.f;
}
__device__ __forceinline__ float bfhi(unsigned int u) {
    union { unsigned int i; float f; } c; c.i = u & 0xffff0000u; return c.f;
}
__device__ __forceinline__ unsigned short f2bf(float f) {
    union { float f; unsigned int i; } c; c.f = f;
    unsigned int i = c.i;
    unsigned int r = (i + 0x7FFFu + ((i >> 16) & 1u)) >> 16;   // RNE
    return (unsigned short)r;
}

__device__ __forceinline__ void gload16(const void* g, void* l) {
    __builtin_amdgcn_global_load_lds((const __attribute__((address_space(1))) void*)g,
                                     (__attribute__((address_space(3))) void*)l, 16, 0, 0);
}

// ---------------------------------------------------------------------------
// Layer-0 GEMM (transform-first): A[M_PAD,768] bf16 @ Wt0[1280,768]^T.
// Double-buffered LDS; XCD-chunked tile remap (A row-panel L2 reuse).
// grid = 8 * 295 (15 tail blocks idle).
// ---------------------------------------------------------------------------
__global__ __launch_bounds__(512) void gemm_l0(
    const unsigned short* __restrict__ A,
    const unsigned short* __restrict__ Bt,
    const float* __restrict__ bias,
    unsigned short* __restrict__ out_root,
    unsigned short* __restrict__ out_msg,
    int K)
{
    __shared__ __align__(16) unsigned short S[2][(128 + 256) * 32];   // 2 x 24576 B

    const int bid  = blockIdx.x;
    const int xcd  = bid & 7;
    const int j    = bid >> 3;                       // 0..294
    const int nrow = (xcd < 5) ? 59 : 58;
    const int rbase = (xcd < 5) ? xcd * 59 : 295 + (xcd - 5) * 58;
    const int rr = j / 5, cc = j % 5;
    if (rr >= nrow) return;
    const int bm = (rbase + rr) * 128;
    const int bn = cc * 256;

    const int tid  = threadIdx.x;
    const int wave = tid >> 6, lane = tid & 63;
    const int wm = (wave & 1) * 64, wn = (wave >> 1) * 64;

    const int lr = lane >> 2;
    const int kg = ((lane & 3) ^ ((lr ^ (lr >> 2)) & 3)) * 8;   // swizzled k-chunk
    const unsigned short* gsrc[3];
    int ldoff[3];
    #pragma unroll
    for (int t = 0; t < 3; ++t) {
        int g = wave * 3 + t;
        if (g < 8) {
            gsrc[t] = A + (size_t)(bm + g * 16 + lr) * K + kg;
            ldoff[t] = g * 512;                       // As region: shorts 0..4095
        } else {
            gsrc[t] = Bt + (size_t)(bn + (g - 8) * 16 + lr) * K + kg;
            ldoff[t] = 4096 + (g - 8) * 512;          // Bs region: shorts 4096..12287
        }
    }

    f32x4 acc[4][4] = {};
    const int fr = lane & 15;
    const int qsw = (((lane >> 4) ^ fr ^ (fr >> 2)) & 3) * 8;

    const int nstep = K >> 5;                         // 24
    gload16(gsrc[0], S[0] + ldoff[0]);
    gload16(gsrc[1], S[0] + ldoff[1]);
    gload16(gsrc[2], S[0] + ldoff[2]);
    __syncthreads();                                  // slice 0 staged

    #pragma unroll 1
    for (int t = 0; t < nstep; ++t) {
        if (t + 1 < nstep) {                          // stage ahead into alt buffer
            unsigned short* nb = S[(t + 1) & 1];
            gload16(gsrc[0] + (t + 1) * 32, nb + ldoff[0]);
            gload16(gsrc[1] + (t + 1) * 32, nb + ldoff[1]);
            gload16(gsrc[2] + (t + 1) * 32, nb + ldoff[2]);
        }
        const unsigned short* cur = S[t & 1];
        short8 a[4], b[4];
        #pragma unroll
        for (int q = 0; q < 4; ++q) {
            a[q] = *(const short8*)&cur[(wm + q * 16 + fr) * 32 + qsw];
            b[q] = *(const short8*)&cur[4096 + (wn + q * 16 + fr) * 32 + qsw];
        }
        #pragma unroll
        for (int mt = 0; mt < 4; ++mt)
            #pragma unroll
            for (int nt = 0; nt < 4; ++nt)
                acc[mt][nt] = __builtin_amdgcn_mfma_f32_16x16x32_bf16(
                    a[mt], b[nt], acc[mt][nt], 0, 0, 0);
        __syncthreads();   // drains vmcnt(0): stage(t+1) done; reads of S[(t+1)&1] done
    }

    const bool is_root = (bn == 0);   // block-uniform
    #pragma unroll
    for (int mt = 0; mt < 4; ++mt) {
        #pragma unroll
        for (int nt = 0; nt < 4; ++nt) {
            int col = bn + wn + nt * 16 + fr;
            float bv = bias[col];
            #pragma unroll
            for (int r = 0; r < 4; ++r) {
                int row = bm + wm + mt * 16 + ((lane >> 4) << 2) + r;
                float v = acc[mt][nt][r] + bv;
                if (is_root) out_root[(size_t)row * 256 + col] = f2bf(v);
                else         out_msg[(size_t)row * 1024 + (col - 256)] = f2bf(v);
            }
        }
    }
}

// ---------------------------------------------------------------------------
// Mid-layer aggregation (de-fused): per node, per relation, mean of h[src]
// -> agg[node][r*256+col] bf16.  1 wave per node, no barriers: the L3 gather
// latency is hidden by TLP (15000 blocks x 4 waves), not by in-block overlap.
// ---------------------------------------------------------------------------
__global__ __launch_bounds__(256) void gather_mean_h(
    const unsigned short* __restrict__ h,       // [M_PAD,256]
    const int* __restrict__ rp4, const int* __restrict__ e_srcs,
    const float* __restrict__ inv4,
    unsigned short* __restrict__ agg)           // [M_PAD,1024]
{
    int node = blockIdx.x * 4 + (threadIdx.x >> 6);
    if (node >= N_NODES) return;
    int lane = threadIdx.x & 63;
    float4 iv = *(const float4*)&inv4[(size_t)node * 4];

    #pragma unroll
    for (int r = 0; r < 4; ++r) {
        int lo = rp4[node * 4 + r], hi = rp4[node * 4 + r + 1];
        float4 s = make_float4(0.f, 0.f, 0.f, 0.f);
        for (int e = lo; e < hi; ++e) {
            int sidx = e_srcs[e];
            uint2 q = *(const uint2*)&h[(size_t)sidx * 256 + lane * 4];
            s.x += bflo(q.x); s.y += bfhi(q.x);
            s.z += bflo(q.y); s.w += bfhi(q.y);
        }
        float f = (r == 0) ? iv.x : (r == 1) ? iv.y : (r == 2) ? iv.z : iv.w;
        ushort4 o;
        o.x = f2bf(s.x * f); o.y = f2bf(s.y * f);
        o.z = f2bf(s.z * f); o.w = f2bf(s.w * f);
        *(ushort4*)&agg[(size_t)node * 1024 + r * 256 + lane * 4] = o;
    }
}

// ---------------------------------------------------------------------------
// Mid-layer GEMM: out = relu([agg | h] @ W + b), K = 1280 (k<1024 from agg,
// k>=1024 from h).  Same proven double-buffered 128x256 structure as gemm_l0.
// grid = 469.
// ---------------------------------------------------------------------------
__global__ __launch_bounds__(512) void gemm_layer(
    const unsigned short* __restrict__ agg,   // [M_PAD,1024]
    const unsigned short* __restrict__ hin,   // [M_PAD,256]
    const unsigned short* __restrict__ Bt,    // W [256 out][1280 k]
    const float* __restrict__ bias,           // [256]
    unsigned short* __restrict__ h_out)       // [M_PAD,256]
{
    __shared__ __align__(16) unsigned short S[2][(128 + 256) * 32];   // 2 x 24576 B

    const int tid  = threadIdx.x;
    const int wave = tid >> 6, lane = tid & 63;
    const int bm = blockIdx.x * 128;
    const int wm = (wave & 1) * 64, wn = (wave >> 1) * 64;

    const int lr = lane >> 2;
    const int kg = ((lane & 3) ^ ((lr ^ (lr >> 2)) & 3)) * 8;

    const unsigned short* src0[3];   // agg base (A groups) or W base (B groups)
    const unsigned short* srcH[3];   // h base (A groups only)
    int ldoff[3];
    bool grpA[3];
    #pragma unroll
    for (int j = 0; j < 3; ++j) {
        int g = wave * 3 + j;
        if (g < 8) {
            grpA[j] = true;
            src0[j] = agg + (size_t)(bm + g * 16 + lr) * 1024 + kg;
            srcH[j] = hin + (size_t)(bm + g * 16 + lr) * 256 + kg;
            ldoff[j] = g * 512;
        } else {
            grpA[j] = false;
            src0[j] = Bt + (size_t)((g - 8) * 16 + lr) * N_TOT + kg;
            srcH[j] = nullptr;
            ldoff[j] = 4096 + (g - 8) * 512;
        }
    }

    f32x4 acc[4][4] = {};
    const int fr = lane & 15;
    const int qsw = (((lane >> 4) ^ fr ^ (fr >> 2)) & 3) * 8;

    auto stage = [&](int t, unsigned short* buf) {
        #pragma unroll
        for (int j = 0; j < 3; ++j) {
            const unsigned short* s;
            if (grpA[j]) s = (t < 32) ? src0[j] + t * 32 : srcH[j] + (t - 32) * 32;
            else         s = src0[j] + t * 32;
            gload16(s, buf + ldoff[j]);
        }
    };

    stage(0, S[0]);
    __syncthreads();

    #pragma unroll 1
    for (int t = 0; t < 40; ++t) {
        if (t + 1 < 40) stage(t + 1, S[(t + 1) & 1]);
        const unsigned short* cur = S[t & 1];
        short8 a[4], b[4];
        #pragma unroll
        for (int q = 0; q < 4; ++q) {
            a[q] = *(const short8*)&cur[(wm + q * 16 + fr) * 32 + qsw];
            b[q] = *(const short8*)&cur[4096 + (wn + q * 16 + fr) * 32 + qsw];
        }
        #pragma unroll
        for (int mt = 0; mt < 4; ++mt)
            #pragma unroll
            for (int nt = 0; nt < 4; ++nt)
                acc[mt][nt] = __builtin_amdgcn_mfma_f32_16x16x32_bf16(
                    a[mt], b[nt], acc[mt][nt], 0, 0, 0);
        __syncthreads();
    }

    #pragma unroll
    for (int mt = 0; mt < 4; ++mt) {
        #pragma unroll
        for (int nt = 0; nt < 4; ++nt) {
            int col = wn + nt * 16 + fr;
            float bv = bias[col];
            #pragma unroll
            for (int r = 0; r < 4; ++r) {
                int row = bm + wm + mt * 16 + ((lane >> 4) << 2) + r;
                float v = fmaxf(acc[mt][nt][r] + bv, 0.f);
                h_out[(size_t)row * 256 + col] = f2bf(v);
            }
        }
    }
}

// ---------------------------------------------------------------------------
// Prep kernels
// ---------------------------------------------------------------------------
__global__ void convert_x(const float* __restrict__ x, unsigned short* __restrict__ xb) {
    size_t i = ((size_t)blockIdx.x * 256 + threadIdx.x) * 4;
    if (i >= (size_t)M_PAD * D_IN) return;
    ushort4 o;
    if (i < (size_t)N_NODES * D_IN) {
        float4 v = *(const float4*)&x[i];
        o.x = f2bf(v.x); o.y = f2bf(v.y); o.z = f2bf(v.z); o.w = f2bf(v.w);
    } else {
        o.x = o.y = o.z = o.w = 0;
    }
    *(ushort4*)&xb[i] = o;
}

__global__ void pack_w0(const float* __restrict__ root0, const float* __restrict__ w0,
                        unsigned short* __restrict__ Wt0) {
    int idx = blockIdx.x * 256 + threadIdx.x;            // Wt0[n][k], [1280 x 768]
    if (idx >= N_TOT * D_IN) return;
    int k = idx % D_IN, n = idx / D_IN;
    float v = (n < 256) ? root0[k * 256 + n]
                        : w0[(((n >> 8) - 1) * D_IN + k) * 256 + (n & 255)];
    Wt0[idx] = f2bf(v);
}

// WtR[l][n][k]: k<1024 -> w_rest[l][k>>8][k&255][n]; k>=1024 -> root_rest[l][k-1024][n]
__global__ void pack_wr(const float* __restrict__ root_rest, const float* __restrict__ w_rest,
                        unsigned short* __restrict__ WtR) {
    int idx = blockIdx.x * 256 + threadIdx.x;
    if (idx >= 5 * 256 * N_TOT) return;
    int k = idx % N_TOT; int t = idx / N_TOT; int n = t & 255; int l = t >> 8;
    float v = (k < 1024)
        ? w_rest[(((l * 4 + (k >> 8)) * 256) + (k & 255)) * 256 + n]
        : root_rest[(l * 256 + (k - 1024)) * 256 + n];
    WtR[idx] = f2bf(v);
}

__global__ void build_bias(const float* __restrict__ b0, float* __restrict__ eb) {
    int i = blockIdx.x * 256 + threadIdx.x;
    if (i < N_TOT) eb[i] = (i < 256) ? b0[i] : 0.f;
}

// ---------------------------------------------------------------------------
// (dst, rel)-sorted CSR over 4*N segments
// ---------------------------------------------------------------------------
__global__ void deg4_count(const int* __restrict__ dst, const int* __restrict__ rel,
                           int* __restrict__ deg4, int E) {
    int e = blockIdx.x * 256 + threadIdx.x;
    if (e < E) atomicAdd(&deg4[dst[e] * 4 + rel[e]], 1);
}

__global__ void invert4(const int* __restrict__ deg4, float* __restrict__ inv4, int n) {
    int i = blockIdx.x * 256 + threadIdx.x;
    if (i < n) inv4[i] = 1.0f / (float)max(deg4[i], 1);
}

__global__ __launch_bounds__(256) void block_sum(const int* __restrict__ deg,
                                                 int* __restrict__ bsum, int n) {
    __shared__ int s[256];
    int i = blockIdx.x * 256 + threadIdx.x;
    s[threadIdx.x] = (i < n) ? deg[i] : 0;
    __syncthreads();
    for (int o = 128; o > 0; o >>= 1) {
        if (threadIdx.x < o) s[threadIdx.x] += s[threadIdx.x + o];
        __syncthreads();
    }
    if (threadIdx.x == 0) bsum[blockIdx.x] = s[0];
}

__global__ __launch_bounds__(1024) void scan_bsum(const int* __restrict__ bsum,
                                                  int* __restrict__ boff, int nb) {
    __shared__ int s[1024];
    int t = threadIdx.x;
    int v0 = (t < nb) ? bsum[t] : 0;
    s[t] = v0;
    __syncthreads();
    for (int o = 1; o < 1024; o <<= 1) {
        int v = (t >= o) ? s[t - o] : 0;
        __syncthreads();
        s[t] += v;
        __syncthreads();
    }
    if (t < nb) boff[t] = s[t] - v0;   // exclusive
}

__global__ __launch_bounds__(256) void block_scan_write(
    const int* __restrict__ deg, const int* __restrict__ boff,
    int* __restrict__ row_ptr, int* __restrict__ cursor, int n, int total) {
    __shared__ int s[256];
    int t = threadIdx.x;
    int i = blockIdx.x * 256 + t;
    int v = (i < n) ? deg[i] : 0;
    s[t] = v;
    __syncthreads();
    for (int o = 1; o < 256; o <<= 1) {
        int u = (t >= o) ? s[t - o] : 0;
        __syncthreads();
        s[t] += u;
        __syncthreads();
    }
    int excl = s[t] - v + boff[blockIdx.x];
    if (i < n) { row_ptr[i] = excl; cursor[i] = excl; }
    if (blockIdx.x == 0 && t == 0) row_ptr[n] = total;
}

__global__ void place_edges4(const int* __restrict__ dst, const int* __restrict__ src,
                             const int* __restrict__ rel, int* __restrict__ cursor,
                             int* __restrict__ e_srcs, int E) {
    int e = blockIdx.x * 256 + threadIdx.x;
    if (e < E) {
        int p = atomicAdd(&cursor[dst[e] * 4 + rel[e]], 1);
        e_srcs[p] = src[e];
    }
}

// ---------------------------------------------------------------------------
// Layer-0 aggregate: h0 = relu(root[n] + sum_r inv_r * sum_e msg[src, r])
// ---------------------------------------------------------------------------
__global__ __launch_bounds__(256) void aggregate0(
    const unsigned short* __restrict__ rootb,   // [M_PAD,256]
    const unsigned short* __restrict__ msg,     // [M_PAD,1024]
    const int* __restrict__ rp4, const int* __restrict__ e_srcs,
    const float* __restrict__ inv4,
    unsigned short* __restrict__ h_out)         // [M_PAD,256]
{
    int node = blockIdx.x * 4 + (threadIdx.x >> 6);
    if (node >= N_NODES) return;
    int lane = threadIdx.x & 63;
    float4 iv = *(const float4*)&inv4[(size_t)node * 4];

    ushort4 rt = *(const ushort4*)&rootb[(size_t)node * 256 + lane * 4];
    float4 acc = make_float4(bf2f(rt.x), bf2f(rt.y), bf2f(rt.z), bf2f(rt.w));

    #pragma unroll
    for (int r = 0; r < 4; ++r) {
        int lo = rp4[(size_t)node * 4 + r], hi = rp4[(size_t)node * 4 + r + 1];
        float f = (r == 0) ? iv.x : (r == 1) ? iv.y : (r == 2) ? iv.z : iv.w;
        float4 s4 = make_float4(0, 0, 0, 0);
        for (int e = lo; e < hi; ++e) {
            int s = e_srcs[e];
            ushort4 m = *(const ushort4*)&msg[(size_t)s * 1024 + (r << 8) + lane * 4];
            s4.x += bf2f(m.x); s4.y += bf2f(m.y);
            s4.z += bf2f(m.z); s4.w += bf2f(m.w);
        }
        acc.x += s4.x * f; acc.y += s4.y * f;
        acc.z += s4.z * f; acc.w += s4.w * f;
    }
    ushort4 o;
    o.x = f2bf(fmaxf(acc.x, 0.f));
    o.y = f2bf(fmaxf(acc.y, 0.f));
    o.z = f2bf(fmaxf(acc.z, 0.f));
    o.w = f2bf(fmaxf(acc.w, 0.f));
    *(ushort4*)&h_out[(size_t)node * 256 + lane * 4] = o;
}

// ---------------------------------------------------------------------------
// Pooling + MLP head
// ---------------------------------------------------------------------------
__global__ __launch_bounds__(256) void pool_kernel(
    const unsigned short* __restrict__ h, const int* __restrict__ batch,
    float* __restrict__ g_feat)
{
    int g = blockIdx.x;
    int t = threadIdx.x;
    __shared__ int s_lo, s_hi;
    if (t == 0) {
        int lo = 0, hi = N_NODES;
        while (lo < hi) { int m = (lo + hi) >> 1; if (batch[m] < g) lo = m + 1; else hi = m; }
        s_lo = lo;
        int lo2 = lo, hi2 = N_NODES;
        while (lo2 < hi2) { int m = (lo2 + hi2) >> 1; if (batch[m] < g + 1) lo2 = m + 1; else hi2 = m; }
        s_hi = lo2;
    }
    __syncthreads();
    int lo = s_lo, hi = s_hi;
    float sum = 0.f, mx = 0.f;   // post-ReLU
    for (int n = lo; n < hi; ++n) {
        float v = bf2f(h[(size_t)n * 256 + t]);
        sum += v;
        mx = fmaxf(mx, v);
    }
    float cnt = (float)(hi - lo);
    g_feat[g * 512 + t]       = sum / fmaxf(cnt, 1.0f);
    g_feat[g * 512 + 256 + t] = (cnt > 0.f) ? mx : 0.f;
}

__global__ __launch_bounds__(128) void mlp_head(
    const float* __restrict__ g_feat,
    const float* __restrict__ fc1_w, const float* __restrict__ fc1_b,
    const float* __restrict__ fc2_w, const float* __restrict__ fc2_b,
    float* __restrict__ out)
{
    __shared__ float gf[512];
    __shared__ float partial[2];
    int g = blockIdx.x, t = threadIdx.x;
    for (int i = t; i < 512; i += 128) gf[i] = g_feat[g * 512 + i];
    __syncthreads();
    float acc = fc1_b[t];
    for (int i = 0; i < 512; ++i) acc += gf[i] * fc1_w[i * 128 + t];
    float h1 = fmaxf(acc, 0.f);
    float v = h1 * fc2_w[t];
    #pragma unroll
    for (int off = 32; off > 0; off >>= 1) v += __shfl_down(v, off);
    if ((t & 63) == 0) partial[t >> 6] = v;
    __syncthreads();
    if (t == 0) {
        float s = partial[0] + partial[1] + fc2_b[0];
        out[g] = 1.0f / (1.0f + expf(-s));
    }
}

// ---------------------------------------------------------------------------
// Launch
// ---------------------------------------------------------------------------
extern "C" void kernel_launch(void* const* d_in, const int* in_sizes, int n_in,
                              void* d_out, int out_size, void* d_ws, size_t ws_size,
                              hipStream_t stream) {
    const float* x          = (const float*)d_in[0];
    const int*   edge_index = (const int*)d_in[1];
    const int*   edge_attr  = (const int*)d_in[2];
    const int*   batch      = (const int*)d_in[3];
    const float* w0         = (const float*)d_in[4];
    const float* root0      = (const float*)d_in[5];
    const float* b0         = (const float*)d_in[6];
    const float* w_rest     = (const float*)d_in[7];
    const float* root_rest  = (const float*)d_in[8];
    const float* b_rest     = (const float*)d_in[9];
    const float* fc1_w      = (const float*)d_in[10];
    const float* fc1_b      = (const float*)d_in[11];
    const float* fc2_w      = (const float*)d_in[12];
    const float* fc2_b      = (const float*)d_in[13];
    float* out = (float*)d_out;

    const int* e_src = edge_index;
    const int* e_dst = edge_index + N_EDGES;

    char* p = (char*)d_ws;
    auto alloc = [&](size_t bytes) { char* q = p; p += (bytes + 255) & ~(size_t)255; return q; };
    unsigned short* x_bf   = (unsigned short*)alloc((size_t)M_PAD * D_IN * 2);   // 92 MB
    unsigned short* msgbuf = (unsigned short*)alloc((size_t)M_PAD * 1024 * 2);   // 123 MB (msg, then agg)
    unsigned short* hA     = (unsigned short*)alloc((size_t)M_PAD * 256 * 2);    // 31 MB
    unsigned short* hB     = (unsigned short*)alloc((size_t)M_PAD * 256 * 2);    // 31 MB
    unsigned short* Wt0    = (unsigned short*)alloc((size_t)N_TOT * D_IN * 2);
    unsigned short* WtR    = (unsigned short*)alloc((size_t)5 * 256 * N_TOT * 2);
    float*          ebias  = (float*)alloc(N_TOT * 4);
    float*          inv4   = (float*)alloc((size_t)N_NODES * 4 * 4);
    float*          g_feat = (float*)alloc((size_t)N_GRAPHS * 512 * 4);
    int*            deg4   = (int*)alloc((size_t)N_NODES * 4 * 4);
    int*            rp4    = (int*)alloc(((size_t)N_NODES * 4 + 1) * 4);
    int*            cursor4= (int*)alloc((size_t)N_NODES * 4 * 4);
    int*            bsum   = (int*)alloc(1024 * 4);
    int*            boff   = (int*)alloc(1024 * 4);
    int*            e_srcs = (int*)alloc((size_t)N_EDGES * 4);

    const int n4 = N_NODES * 4;                 // 240000
    const int nscan4 = cdiv(n4, 256);           // 938

    // --- prep ---
    hipMemsetAsync(deg4, 0, (size_t)n4 * 4, stream);
    convert_x<<<cdiv(M_PAD * D_IN / 4, 256), 256, 0, stream>>>(x, x_bf);
    pack_w0<<<cdiv(N_TOT * D_IN, 256), 256, 0, stream>>>(root0, w0, Wt0);
    pack_wr<<<cdiv(5 * 256 * N_TOT, 256), 256, 0, stream>>>(root_rest, w_rest, WtR);
    build_bias<<<cdiv(N_TOT, 256), 256, 0, stream>>>(b0, ebias);
    deg4_count<<<cdiv(N_EDGES, 256), 256, 0, stream>>>(e_dst, edge_attr, deg4, N_EDGES);
    invert4<<<cdiv(n4, 256), 256, 0, stream>>>(deg4, inv4, n4);
    block_sum<<<nscan4, 256, 0, stream>>>(deg4, bsum, n4);
    scan_bsum<<<1, 1024, 0, stream>>>(bsum, boff, nscan4);
    block_scan_write<<<nscan4, 256, 0, stream>>>(deg4, boff, rp4, cursor4, n4, N_EDGES);
    place_edges4<<<cdiv(N_EDGES, 256), 256, 0, stream>>>(e_dst, e_src, edge_attr,
                                                         cursor4, e_srcs, N_EDGES);

    // --- layer 0: transform-first GEMM + edge-parallel aggregate ---
    gemm_l0<<<8 * 295, 512, 0, stream>>>(x_bf, Wt0, ebias, hB, msgbuf, D_IN);
    aggregate0<<<cdiv(N_NODES, 4), 256, 0, stream>>>(hB, msgbuf, rp4, e_srcs, inv4, hA);

    // --- layers 1..5: aggregate-first (barrier-free TLP gather) + dense GEMM ---
    unsigned short* cur = hA;
    unsigned short* nxt = hB;
    for (int L = 1; L < N_LAYERS; ++L) {
        gather_mean_h<<<cdiv(N_NODES, 4), 256, 0, stream>>>(cur, rp4, e_srcs, inv4, msgbuf);
        gemm_layer<<<M_PAD / 128, 512, 0, stream>>>(
            msgbuf, cur, WtR + (size_t)(L - 1) * 256 * N_TOT, b_rest + (size_t)(L - 1) * 256,
            nxt);
        unsigned short* t = cur; cur = nxt; nxt = t;
    }
    // final h in cur

    pool_kernel<<<N_GRAPHS, 256, 0, stream>>>(cur, batch, g_feat);
    mlp_head<<<N_GRAPHS, 128, 0, stream>>>(g_feat, fc1_w, fc1_b, fc2_w, fc2_b, out);
}